// Round 10
// baseline (247.267 us; speedup 1.0000x reference)
//
#include <hip/hip_runtime.h>
#include <math.h>

// Problem constants (B=8, C=192, H=W=32)
#define BB 8
#define CC 192
#define LL 1024
#define RT 8192         // total rows = BB*LL
#define DI 384          // d_inner
#define DT_RANK 12
#define NS 16           // D_STATE
#define NSEG 16
#define SEGL 64

// ---------------------------------------------------------------------------
// K1: W2[j,c'] = sum_c in_proj_w[j,c]*proj_w[c,c'];  bias2[j] = in_proj_w[j,:]·proj_b
__global__ void fuse_w_kernel(const float* __restrict__ in_proj_w,
                              const float* __restrict__ proj_w,
                              const float* __restrict__ proj_b,
                              float* __restrict__ W2, float* __restrict__ bias2) {
    int j = blockIdx.x;
    int cp = threadIdx.x;
    __shared__ float wrow[CC];
    wrow[cp] = in_proj_w[j * CC + cp];
    __syncthreads();
    float acc = 0.f;
#pragma unroll 4
    for (int c = 0; c < CC; ++c) acc = fmaf(wrow[c], proj_w[c * CC + cp], acc);
    W2[j * CC + cp] = acc;
    if (cp == 0) {
        float b = 0.f;
        for (int c = 0; c < CC; ++c) b = fmaf(wrow[c], proj_b[c], b);
        bias2[j] = b;
    }
}

// ---------------------------------------------------------------------------
// K2: xzT[j, row] = sum_c x[b, c, l] * W2[j, c] + bias2[j]   (row = b*1024+l)
// 64 rows x 96 j tile, grid (128,8) = 1024 blocks = 4 blocks/CU (R9 showed
// the old 512-block config was wave-starved: VALUBusy 38% == pure-FMA floor).
// Microtile 4r x 6j; K-stage 32 with register-prefetch staging.
// z-half blocks (j0>=384) apply silu in the epilogue -> zsT directly.
__global__ __launch_bounds__(256) void gemm_xz(const float* __restrict__ x,
                                               const float* __restrict__ W2,
                                               const float* __restrict__ bias2,
                                               float* __restrict__ xzT) {
    __shared__ float As[32][68];   // [k][row]  8.7 KB
    __shared__ float Bs[32][100];  // [k][j]   12.8 KB
    int r0 = blockIdx.x * 64;
    int j0 = blockIdx.y * 96;
    int b  = r0 >> 10;
    int l0 = r0 & 1023;
    int tid = threadIdx.x;
    int tx = tid & 15;   // row quad
    int ty = tid >> 4;   // j sextet
    float acc[6][4] = {};
    const float* xb = x + b * CC * LL;
    float4 ar[2], br[3];
    // A: idx = tid + it*256 -> k = idx>>4, r4 = (idx&15)*4   (2 per thread)
    // B: idx = tid + it*256 -> j = idx>>3, kq = (idx&7)*4    (3 per thread)
#define LOAD_REGS(k0_)                                                       \
    _Pragma("unroll") for (int it = 0; it < 2; ++it) {                       \
        int idx = tid + it * 256;                                            \
        ar[it] = *(const float4*)&xb[((k0_) + (idx >> 4)) * LL + l0 + (idx & 15) * 4]; \
    }                                                                        \
    _Pragma("unroll") for (int it = 0; it < 3; ++it) {                       \
        int idx = tid + it * 256;                                            \
        br[it] = *(const float4*)&W2[(j0 + (idx >> 3)) * CC + (k0_) + (idx & 7) * 4]; \
    }
    LOAD_REGS(0);
    for (int k0 = 0; k0 < CC; k0 += 32) {
#pragma unroll
        for (int it = 0; it < 2; ++it) {
            int idx = tid + it * 256;
            *(float4*)&As[idx >> 4][(idx & 15) * 4] = ar[it];
        }
#pragma unroll
        for (int it = 0; it < 3; ++it) {
            int idx = tid + it * 256;
            int j = idx >> 3, kq = (idx & 7) * 4;
            Bs[kq + 0][j] = br[it].x; Bs[kq + 1][j] = br[it].y;
            Bs[kq + 2][j] = br[it].z; Bs[kq + 3][j] = br[it].w;
        }
        __syncthreads();
        if (k0 + 32 < CC) { LOAD_REGS(k0 + 32); }   // prefetch next stage
#pragma unroll
        for (int k = 0; k < 32; ++k) {
            float4 av = *(const float4*)&As[k][tx * 4];
            float arr[4] = {av.x, av.y, av.z, av.w};
            float brr[6];
#pragma unroll
            for (int q = 0; q < 6; ++q) brr[q] = Bs[k][ty * 6 + q];
#pragma unroll
            for (int jc = 0; jc < 6; ++jc)
#pragma unroll
                for (int rc = 0; rc < 4; ++rc)
                    acc[jc][rc] = fmaf(brr[jc], arr[rc], acc[jc][rc]);
        }
        __syncthreads();
    }
#undef LOAD_REGS
    bool is_z = (j0 >= DI);
#pragma unroll
    for (int jc = 0; jc < 6; ++jc) {
        int j = j0 + ty * 6 + jc;
        float bval = bias2[j];
        float o[4];
#pragma unroll
        for (int rc = 0; rc < 4; ++rc) o[rc] = acc[jc][rc] + bval;
        if (is_z) {
#pragma unroll
            for (int rc = 0; rc < 4; ++rc)
                o[rc] = __fdividef(o[rc], 1.f + __expf(-o[rc]));
        }
        *(float4*)&xzT[j * RT + r0 + tx * 4] = make_float4(o[0], o[1], o[2], o[3]);
    }
}

// ---------------------------------------------------------------------------
// K3: skinny GEMM with fused causal depthwise conv (k=4) + silu in staging.
// xdT[m][row] = sum_k xproj_w[m][k] * silu(conv(xz))[k][row]
// Side-writes xcT (blockIdx.y==0 only) for the scan kernels.
__global__ __launch_bounds__(512) void xproj_conv_gemm(const float* __restrict__ xzT,
                                                       const float* __restrict__ conv_w,
                                                       const float* __restrict__ conv_b,
                                                       const float* __restrict__ aw,
                                                       float* __restrict__ xcT,
                                                       float* __restrict__ xdT) {
    __shared__ float Bs[32][64];
    int col0 = blockIdx.x * 64;
    int tid = threadIdx.x;
    int col = tid & 63, mg = tid >> 6;          // mg wave-uniform -> scalar A loads
    int mb = blockIdx.y * 24 + mg * 3;
    const float* a0 = aw + min(mb + 0, 43) * DI;
    const float* a1 = aw + min(mb + 1, 43) * DI;
    const float* a2 = aw + min(mb + 2, 43) * DI;
    float acc0 = 0.f, acc1 = 0.f, acc2 = 0.f;
    int ks = tid >> 4, c4 = (tid & 15) * 4;
    bool atL0 = ((col0 & 1023) == 0) && (c4 == 0);   // conv zero-pad boundary
    bool wr = (blockIdx.y == 0);
    for (int k0 = 0; k0 < DI; k0 += 32) {
        int dch = k0 + ks;
        const float* src = xzT + (size_t)dch * RT + col0 + c4;
        float4 cur = *(const float4*)src;
        float4 prev = make_float4(0.f, 0.f, 0.f, 0.f);
        if (!atL0) prev = *(const float4*)(src - 4);
        float4 w4 = *(const float4*)&conv_w[dch * 4];   // w0=x w1=y w2=z w3=w
        float bb = conv_b[dch];
        float v0 = bb + w4.w * cur.x + w4.z * prev.w + w4.y * prev.z + w4.x * prev.y;
        float v1 = bb + w4.w * cur.y + w4.z * cur.x  + w4.y * prev.w + w4.x * prev.z;
        float v2 = bb + w4.w * cur.z + w4.z * cur.y  + w4.y * cur.x  + w4.x * prev.w;
        float v3 = bb + w4.w * cur.w + w4.z * cur.z  + w4.y * cur.y  + w4.x * cur.x;
        float4 o;
        o.x = __fdividef(v0, 1.f + __expf(-v0));
        o.y = __fdividef(v1, 1.f + __expf(-v1));
        o.z = __fdividef(v2, 1.f + __expf(-v2));
        o.w = __fdividef(v3, 1.f + __expf(-v3));
        *(float4*)&Bs[ks][c4] = o;
        if (wr) *(float4*)&xcT[(size_t)dch * RT + col0 + c4] = o;
        __syncthreads();
#pragma unroll
        for (int k = 0; k < 32; ++k) {
            float bv = Bs[k][col];
            acc0 = fmaf(a0[k0 + k], bv, acc0);
            acc1 = fmaf(a1[k0 + k], bv, acc1);
            acc2 = fmaf(a2[k0 + k], bv, acc2);
        }
        __syncthreads();
    }
    if (mb + 0 < 44) xdT[(mb + 0) * RT + col0 + col] = acc0;
    if (mb + 1 < 44) xdT[(mb + 1) * RT + col0 + col] = acc1;
    if (mb + 2 < 44) xdT[(mb + 2) * RT + col0 + col] = acc2;
}

// ---------------------------------------------------------------------------
// DPP 16-lane butterfly sum (lane-group = state index n)
__device__ __forceinline__ float rsum16(float x) {
    int v;
    v = __float_as_int(x);
    x += __int_as_float(__builtin_amdgcn_update_dpp(0, v, 0x128, 0xF, 0xF, true)); // ror 8
    v = __float_as_int(x);
    x += __int_as_float(__builtin_amdgcn_update_dpp(0, v, 0x124, 0xF, 0xF, true)); // ror 4
    v = __float_as_int(x);
    x += __int_as_float(__builtin_amdgcn_update_dpp(0, v, 0x122, 0xF, 0xF, true)); // ror 2
    v = __float_as_int(x);
    x += __int_as_float(__builtin_amdgcn_update_dpp(0, v, 0x121, 0xF, 0xF, true)); // ror 1
    return x;
}

// ---------------------------------------------------------------------------
// K4a: per-segment scan from h=0. Whole 64-row segment staged once (one
// coalesced burst, 2 barriers total), then 64 scan steps run barrier-free
// from LDS. dt computed inline. Emits P = prod(dA), Hf = final h.
// grid (16 seg, 24 dblk, 8 b), block 256.
__global__ __launch_bounds__(256) void scan_part1(const float* __restrict__ xdT,
                                                  const float* __restrict__ xcT,
                                                  const float* __restrict__ dtw,
                                                  const float* __restrict__ dtb,
                                                  const float* __restrict__ A_log,
                                                  float* __restrict__ P,
                                                  float* __restrict__ Hf) {
    __shared__ float dt_s[16][68], g_s[16][68], B_s[16][68];
    __shared__ float dtr_s[12][68];
    __shared__ float dtw_s[192];
    __shared__ float dtb_s[16];
    int seg = blockIdx.x, d0 = blockIdx.y * 16, b = blockIdx.z;
    int row0 = b * LL + seg * SEGL;
    int tid = threadIdx.x;
    int lane = tid & 63;
    int n = lane & 15;
    int dl = ((tid >> 6) << 2) | (lane >> 4);
    int tdd = tid >> 4, ti = tid & 15;
    if (tid < 192) dtw_s[tid] = dtw[d0 * DT_RANK + tid];
    if (tid < 16)  dtb_s[tid] = dtb[d0 + tid];
    float a = -__expf(A_log[(d0 + dl) * NS + n]);
    // stage B (16x64) and dtr (12x64); xc into regs
    *(float4*)&B_s[tdd][ti * 4] =
        *(const float4*)&xdT[(12 + tdd) * RT + row0 + ti * 4];
    if (tid < 192)
        *(float4*)&dtr_s[tid >> 4][(tid & 15) * 4] =
            *(const float4*)&xdT[(tid >> 4) * RT + row0 + (tid & 15) * 4];
    float4 xv4 = *(const float4*)&xcT[(d0 + tdd) * RT + row0 + ti * 4];
    __syncthreads();
    // dt/g for this thread's 4 columns
    float dtbv = dtb_s[tdd];
#pragma unroll
    for (int q = 0; q < 4; ++q) {
        int col = ti * 4 + q;
        float acc = dtbv;
#pragma unroll
        for (int rr = 0; rr < DT_RANK; ++rr)
            acc = fmaf(dtr_s[rr][col], dtw_s[tdd * DT_RANK + rr], acc);
        float dtv = fmaxf(acc, 0.f) + __logf(1.f + __expf(-fabsf(acc)));
        dt_s[tdd][col] = dtv;
        g_s[tdd][col]  = dtv * (&xv4.x)[q];
    }
    __syncthreads();
    // barrier-free 64-step scan
    float h = 0.f, Pacc = 1.f;
#pragma unroll
    for (int i = 0; i < SEGL; ++i) {
        float e = __expf(dt_s[dl][i] * a);
        Pacc *= e;
        h = fmaf(e, h, g_s[dl][i] * B_s[n][i]);
    }
    int idx = ((seg * BB + b) * DI + d0 + dl) * NS + n;
    P[idx] = Pacc;
    Hf[idx] = h;
}

// ---------------------------------------------------------------------------
// K4b: rescan each segment from folded h_init; 64 steps barrier-free with
// DPP rsum16 + rotating lane-capture epilogue (no LDS round-trip); direct
// per-lane y writes (4x64B per wave, coalesced within 16-lane groups).
__global__ __launch_bounds__(256) void scan_part2(const float* __restrict__ xdT,
                                                  const float* __restrict__ xcT,
                                                  const float* __restrict__ zsT,
                                                  const float* __restrict__ dtw,
                                                  const float* __restrict__ dtb,
                                                  const float* __restrict__ P,
                                                  const float* __restrict__ Hf,
                                                  const float* __restrict__ A_log,
                                                  const float* __restrict__ Dp,
                                                  float* __restrict__ yT) {
    __shared__ float dt_s[16][68], g_s[16][68], B_s[16][68], C_s[16][68],
                     xc_s[16][68];
    __shared__ float dtr_s[12][68];
    __shared__ float dtw_s[192];
    __shared__ float dtb_s[16];
    int seg = blockIdx.x, d0 = blockIdx.y * 16, b = blockIdx.z;
    int row0 = b * LL + seg * SEGL;
    int tid = threadIdx.x;
    int lane = tid & 63;
    int n = lane & 15;
    int dl = ((tid >> 6) << 2) | (lane >> 4);
    int d = d0 + dl;
    int tdd = tid >> 4, ti = tid & 15;
    if (tid < 192) dtw_s[tid] = dtw[d0 * DT_RANK + tid];
    if (tid < 16)  dtb_s[tid] = dtb[d0 + tid];
    float a = -__expf(A_log[d * NS + n]);
    float Dpv = Dp[d];
    // stage B, C (16x64) and dtr (12x64); xc into regs
    *(float4*)&B_s[tdd][ti * 4] =
        *(const float4*)&xdT[(12 + tdd) * RT + row0 + ti * 4];
    *(float4*)&C_s[tdd][ti * 4] =
        *(const float4*)&xdT[(28 + tdd) * RT + row0 + ti * 4];
    if (tid < 192)
        *(float4*)&dtr_s[tid >> 4][(tid & 15) * 4] =
            *(const float4*)&xdT[(tid >> 4) * RT + row0 + (tid & 15) * 4];
    float4 xv4 = *(const float4*)&xcT[(d0 + tdd) * RT + row0 + ti * 4];
    // h_init: fold earlier segments' summaries (coalesced per wave)
    float h = 0.f;
    for (int s = 0; s < seg; ++s) {
        int off = ((s * BB + b) * DI + d) * NS + n;
        h = fmaf(P[off], h, Hf[off]);
    }
    __syncthreads();
    float dtbv = dtb_s[tdd];
#pragma unroll
    for (int q = 0; q < 4; ++q) {
        int col = ti * 4 + q;
        float acc = dtbv;
#pragma unroll
        for (int rr = 0; rr < DT_RANK; ++rr)
            acc = fmaf(dtr_s[rr][col], dtw_s[tdd * DT_RANK + rr], acc);
        float dtv = fmaxf(acc, 0.f) + __logf(1.f + __expf(-fabsf(acc)));
        dt_s[tdd][col] = dtv;
        float xcv = (&xv4.x)[q];
        g_s[tdd][col]  = dtv * xcv;
        xc_s[tdd][col] = xcv;
    }
    __syncthreads();
    // barrier-free scan: 4 windows of 16 steps; lane n captures step i%16==n
#pragma unroll
    for (int w = 0; w < 4; ++w) {
        int i0 = w * 16;
        float scap = 0.f;
#pragma unroll
        for (int j = 0; j < 16; ++j) {
            int i = i0 + j;
            float e = __expf(dt_s[dl][i] * a);
            h = fmaf(e, h, g_s[dl][i] * B_s[n][i]);
            float s = rsum16(h * C_s[n][i]);
            scap = (n == j) ? s : scap;
        }
        float xcv = xc_s[dl][i0 + n];
        float zsv = zsT[(size_t)(d0 + dl) * RT + row0 + i0 + n];
        yT[(size_t)(d0 + dl) * RT + row0 + i0 + n] = fmaf(xcv, Dpv, scap) * zsv;
    }
}

// ---------------------------------------------------------------------------
// K5: out[b, c, l] = sum_d yT[d, row] * out_w[c, d]
// 64x64 tile, 4x4 microtile, K-stage 32, register double-buffered staging.
// grid (128, 3).
__global__ __launch_bounds__(256) void gemm_out(const float* __restrict__ yT,
                                                const float* __restrict__ out_w,
                                                float* __restrict__ out) {
    __shared__ float As[32][69];  // [k][row]
    __shared__ float Bs[32][69];  // [k][c]
    int r0 = blockIdx.x * 64;
    int c0 = blockIdx.y * 64;
    int b = r0 >> 10, l0 = r0 & 1023;
    int tid = threadIdx.x;
    int tx = tid & 15;   // -> row
    int ty = tid >> 4;   // -> c
    float acc[4][4] = {};  // [cc][rc]
    float4 ar[2], br[2];
#define LOAD_REGS(k0_)                                                       \
    _Pragma("unroll") for (int it = 0; it < 2; ++it) {                       \
        int idx = tid + it * 256;                                            \
        ar[it] = *(const float4*)&yT[((k0_) + (idx >> 4)) * RT + r0 + (idx & 15) * 4]; \
        br[it] = *(const float4*)&out_w[(c0 + (idx >> 3)) * DI + (k0_) + (idx & 7) * 4]; \
    }
    LOAD_REGS(0);
    for (int k0 = 0; k0 < DI; k0 += 32) {
#pragma unroll
        for (int it = 0; it < 2; ++it) {
            int idx = tid + it * 256;
            *(float4*)&As[idx >> 4][(idx & 15) * 4] = ar[it];
            int c = idx >> 3, kq = (idx & 7) * 4;
            Bs[kq + 0][c] = br[it].x; Bs[kq + 1][c] = br[it].y;
            Bs[kq + 2][c] = br[it].z; Bs[kq + 3][c] = br[it].w;
        }
        __syncthreads();
        if (k0 + 32 < DI) { LOAD_REGS(k0 + 32); }   // prefetch next stage
#pragma unroll
        for (int k = 0; k < 32; ++k) {
            float4 av = *(const float4*)&As[k][tx * 4];
            float4 bv = *(const float4*)&Bs[k][ty * 4];
            acc[0][0] = fmaf(bv.x, av.x, acc[0][0]);
            acc[0][1] = fmaf(bv.x, av.y, acc[0][1]);
            acc[0][2] = fmaf(bv.x, av.z, acc[0][2]);
            acc[0][3] = fmaf(bv.x, av.w, acc[0][3]);
            acc[1][0] = fmaf(bv.y, av.x, acc[1][0]);
            acc[1][1] = fmaf(bv.y, av.y, acc[1][1]);
            acc[1][2] = fmaf(bv.y, av.z, acc[1][2]);
            acc[1][3] = fmaf(bv.y, av.w, acc[1][3]);
            acc[2][0] = fmaf(bv.z, av.x, acc[2][0]);
            acc[2][1] = fmaf(bv.z, av.y, acc[2][1]);
            acc[2][2] = fmaf(bv.z, av.z, acc[2][2]);
            acc[2][3] = fmaf(bv.z, av.w, acc[2][3]);
            acc[3][0] = fmaf(bv.w, av.x, acc[3][0]);
            acc[3][1] = fmaf(bv.w, av.y, acc[3][1]);
            acc[3][2] = fmaf(bv.w, av.z, acc[3][2]);
            acc[3][3] = fmaf(bv.w, av.w, acc[3][3]);
        }
        __syncthreads();
    }
#undef LOAD_REGS
    float* ob = out + b * CC * LL;
#pragma unroll
    for (int ic = 0; ic < 4; ++ic) {
        float4 o;
        o.x = acc[ic][0]; o.y = acc[ic][1]; o.z = acc[ic][2]; o.w = acc[ic][3];
        *(float4*)&ob[(c0 + ty * 4 + ic) * LL + l0 + tx * 4] = o;
    }
}

// ---------------------------------------------------------------------------
extern "C" void kernel_launch(void* const* d_in, const int* in_sizes, int n_in,
                              void* d_out, int out_size, void* d_ws, size_t ws_size,
                              hipStream_t stream) {
    const float* x         = (const float*)d_in[0];
    const float* proj_w    = (const float*)d_in[1];
    const float* proj_b    = (const float*)d_in[2];
    const float* in_proj_w = (const float*)d_in[3];
    const float* conv_w    = (const float*)d_in[4];
    const float* conv_b    = (const float*)d_in[5];
    const float* xproj_w   = (const float*)d_in[6];
    const float* dtproj_w  = (const float*)d_in[7];
    const float* dtproj_b  = (const float*)d_in[8];
    const float* A_log     = (const float*)d_in[9];
    const float* Dp        = (const float*)d_in[10];
    const float* out_w     = (const float*)d_in[11];
    float* out = (float*)d_out;

    float* ws    = (float*)d_ws;
    float* W2    = ws;                    // 147456
    float* bias2 = W2 + 147456;           // 768
    float* xzT   = bias2 + 768;           // 768*8192 = 6291456 (x raw, z silu'd)
    float* xcT   = xzT + 6291456;         // 3145728
    float* yT    = xcT + 3145728;         // 3145728
    float* xdT   = yT + 3145728;          // 44*8192 = 360448 (0-11 dtr, 12-27 B, 28-43 C)
    float* P     = xdT + 360448;          // 786432
    float* Hf    = P + 786432;            // 786432
    float* zsT   = xzT + DI * RT;         // z half, silu applied by gemm_xz epilogue

    fuse_w_kernel<<<768, 192, 0, stream>>>(in_proj_w, proj_w, proj_b, W2, bias2);
    gemm_xz<<<dim3(128, 8), 256, 0, stream>>>(x, W2, bias2, xzT);
    xproj_conv_gemm<<<dim3(128, 2), 512, 0, stream>>>(xzT, conv_w, conv_b,
                                                      xproj_w, xcT, xdT);
    scan_part1<<<dim3(16, 24, 8), 256, 0, stream>>>(xdT, xcT, dtproj_w, dtproj_b,
                                                    A_log, P, Hf);
    scan_part2<<<dim3(16, 24, 8), 256, 0, stream>>>(xdT, xcT, zsT, dtproj_w, dtproj_b,
                                                    P, Hf, A_log, Dp, yT);
    gemm_out<<<dim3(128, 3), 256, 0, stream>>>(yT, out_w, out);
}

// Round 11
// 244.688 us; speedup vs baseline: 1.0105x; 1.0105x over previous
//
#include <hip/hip_runtime.h>
#include <math.h>

// Problem constants (B=8, C=192, H=W=32)
#define BB 8
#define CC 192
#define LL 1024
#define RT 8192         // total rows = BB*LL
#define DI 384          // d_inner
#define DT_RANK 12
#define NS 16           // D_STATE
#define NSEG 16
#define SEGL 64

// ---------------------------------------------------------------------------
// K1: W2[j,c'] = sum_c in_proj_w[j,c]*proj_w[c,c'];  bias2[j] = in_proj_w[j,:]·proj_b
__global__ void fuse_w_kernel(const float* __restrict__ in_proj_w,
                              const float* __restrict__ proj_w,
                              const float* __restrict__ proj_b,
                              float* __restrict__ W2, float* __restrict__ bias2) {
    int j = blockIdx.x;
    int cp = threadIdx.x;
    __shared__ float wrow[CC];
    wrow[cp] = in_proj_w[j * CC + cp];
    __syncthreads();
    float acc = 0.f;
#pragma unroll 4
    for (int c = 0; c < CC; ++c) acc = fmaf(wrow[c], proj_w[c * CC + cp], acc);
    W2[j * CC + cp] = acc;
    if (cp == 0) {
        float b = 0.f;
        for (int c = 0; c < CC; ++c) b = fmaf(wrow[c], proj_b[c], b);
        bias2[j] = b;
    }
}

// ---------------------------------------------------------------------------
// K2: xzT[j, row] = sum_c x[b, c, l] * W2[j, c] + bias2[j]   (row = b*1024+l)
// LDS-FREE design (R10 showed any LDS-tiled fp32 GEMM here is LDS-issue-bound,
// VALUBusy pinned ~40%): lane = row (x loads coalesced, L2-resident),
// W2 wave-uniform (j-strip per wave via readfirstlane, k loop-uniform ->
// s_load into SGPRs; FMA reads weight from SGPR). Zero LDS, zero barriers.
// Wave = 128 rows (float2/lane) x 16 j. grid (64 rowtiles, 12 jtiles), 256 thr.
__global__ __launch_bounds__(256) void gemm_xz(const float* __restrict__ x,
                                               const float* __restrict__ W2,
                                               const float* __restrict__ bias2,
                                               float* __restrict__ xzT) {
    int wv = __builtin_amdgcn_readfirstlane(threadIdx.x >> 6);  // wave-uniform
    int lane = threadIdx.x & 63;
    int r0 = blockIdx.x * 128;          // row tile (never crosses b boundary)
    int b  = r0 >> 10;
    int l0 = r0 & 1023;
    int jw = blockIdx.y * 64 + wv * 16; // this wave's 16-j strip
    const float* xb = x + (size_t)b * CC * LL + l0 + lane * 2;
    const float* wbase = W2 + (size_t)jw * CC;
    float2 acc[16];
#pragma unroll
    for (int ji = 0; ji < 16; ++ji) acc[ji] = make_float2(0.f, 0.f);
#pragma unroll 4
    for (int k = 0; k < CC; ++k) {
        float2 a = *(const float2*)&xb[(size_t)k * LL];
#pragma unroll
        for (int ji = 0; ji < 16; ++ji) {
            float w = wbase[ji * CC + k];          // uniform addr -> s_load
            acc[ji].x = fmaf(w, a.x, acc[ji].x);
            acc[ji].y = fmaf(w, a.y, acc[ji].y);
        }
    }
    bool is_z = (jw >= DI);                        // wave-uniform
#pragma unroll
    for (int ji = 0; ji < 16; ++ji) {
        int j = jw + ji;
        float bval = bias2[j];
        float ox = acc[ji].x + bval;
        float oy = acc[ji].y + bval;
        if (is_z) {
            ox = __fdividef(ox, 1.f + __expf(-ox));
            oy = __fdividef(oy, 1.f + __expf(-oy));
        }
        *(float2*)&xzT[(size_t)j * RT + r0 + lane * 2] = make_float2(ox, oy);
    }
}

// ---------------------------------------------------------------------------
// K3: skinny GEMM with fused causal depthwise conv (k=4) + silu in staging.
// xdT[m][row] = sum_k xproj_w[m][k] * silu(conv(xz))[k][row]
// Side-writes xcT (blockIdx.y==0 only) for the scan kernels.
__global__ __launch_bounds__(512) void xproj_conv_gemm(const float* __restrict__ xzT,
                                                       const float* __restrict__ conv_w,
                                                       const float* __restrict__ conv_b,
                                                       const float* __restrict__ aw,
                                                       float* __restrict__ xcT,
                                                       float* __restrict__ xdT) {
    __shared__ float Bs[32][64];
    int col0 = blockIdx.x * 64;
    int tid = threadIdx.x;
    int col = tid & 63, mg = tid >> 6;          // mg wave-uniform -> scalar A loads
    int mb = blockIdx.y * 24 + mg * 3;
    const float* a0 = aw + min(mb + 0, 43) * DI;
    const float* a1 = aw + min(mb + 1, 43) * DI;
    const float* a2 = aw + min(mb + 2, 43) * DI;
    float acc0 = 0.f, acc1 = 0.f, acc2 = 0.f;
    int ks = tid >> 4, c4 = (tid & 15) * 4;
    bool atL0 = ((col0 & 1023) == 0) && (c4 == 0);   // conv zero-pad boundary
    bool wr = (blockIdx.y == 0);
    for (int k0 = 0; k0 < DI; k0 += 32) {
        int dch = k0 + ks;
        const float* src = xzT + (size_t)dch * RT + col0 + c4;
        float4 cur = *(const float4*)src;
        float4 prev = make_float4(0.f, 0.f, 0.f, 0.f);
        if (!atL0) prev = *(const float4*)(src - 4);
        float4 w4 = *(const float4*)&conv_w[dch * 4];   // w0=x w1=y w2=z w3=w
        float bb = conv_b[dch];
        float v0 = bb + w4.w * cur.x + w4.z * prev.w + w4.y * prev.z + w4.x * prev.y;
        float v1 = bb + w4.w * cur.y + w4.z * cur.x  + w4.y * prev.w + w4.x * prev.z;
        float v2 = bb + w4.w * cur.z + w4.z * cur.y  + w4.y * cur.x  + w4.x * prev.w;
        float v3 = bb + w4.w * cur.w + w4.z * cur.z  + w4.y * cur.y  + w4.x * cur.x;
        float4 o;
        o.x = __fdividef(v0, 1.f + __expf(-v0));
        o.y = __fdividef(v1, 1.f + __expf(-v1));
        o.z = __fdividef(v2, 1.f + __expf(-v2));
        o.w = __fdividef(v3, 1.f + __expf(-v3));
        *(float4*)&Bs[ks][c4] = o;
        if (wr) *(float4*)&xcT[(size_t)dch * RT + col0 + c4] = o;
        __syncthreads();
#pragma unroll
        for (int k = 0; k < 32; ++k) {
            float bv = Bs[k][col];
            acc0 = fmaf(a0[k0 + k], bv, acc0);
            acc1 = fmaf(a1[k0 + k], bv, acc1);
            acc2 = fmaf(a2[k0 + k], bv, acc2);
        }
        __syncthreads();
    }
    if (mb + 0 < 44) xdT[(mb + 0) * RT + col0 + col] = acc0;
    if (mb + 1 < 44) xdT[(mb + 1) * RT + col0 + col] = acc1;
    if (mb + 2 < 44) xdT[(mb + 2) * RT + col0 + col] = acc2;
}

// ---------------------------------------------------------------------------
// DPP 16-lane butterfly sum (lane-group = state index n)
__device__ __forceinline__ float rsum16(float x) {
    int v;
    v = __float_as_int(x);
    x += __int_as_float(__builtin_amdgcn_update_dpp(0, v, 0x128, 0xF, 0xF, true)); // ror 8
    v = __float_as_int(x);
    x += __int_as_float(__builtin_amdgcn_update_dpp(0, v, 0x124, 0xF, 0xF, true)); // ror 4
    v = __float_as_int(x);
    x += __int_as_float(__builtin_amdgcn_update_dpp(0, v, 0x122, 0xF, 0xF, true)); // ror 2
    v = __float_as_int(x);
    x += __int_as_float(__builtin_amdgcn_update_dpp(0, v, 0x121, 0xF, 0xF, true)); // ror 1
    return x;
}

// ---------------------------------------------------------------------------
// K4a: per-segment scan from h=0. Whole 64-row segment staged once, then 64
// scan steps barrier-free from LDS. dt inline. Emits P, Hf.
__global__ __launch_bounds__(256) void scan_part1(const float* __restrict__ xdT,
                                                  const float* __restrict__ xcT,
                                                  const float* __restrict__ dtw,
                                                  const float* __restrict__ dtb,
                                                  const float* __restrict__ A_log,
                                                  float* __restrict__ P,
                                                  float* __restrict__ Hf) {
    __shared__ float dt_s[16][68], g_s[16][68], B_s[16][68];
    __shared__ float dtr_s[12][68];
    __shared__ float dtw_s[192];
    __shared__ float dtb_s[16];
    int seg = blockIdx.x, d0 = blockIdx.y * 16, b = blockIdx.z;
    int row0 = b * LL + seg * SEGL;
    int tid = threadIdx.x;
    int lane = tid & 63;
    int n = lane & 15;
    int dl = ((tid >> 6) << 2) | (lane >> 4);
    int tdd = tid >> 4, ti = tid & 15;
    if (tid < 192) dtw_s[tid] = dtw[d0 * DT_RANK + tid];
    if (tid < 16)  dtb_s[tid] = dtb[d0 + tid];
    float a = -__expf(A_log[(d0 + dl) * NS + n]);
    *(float4*)&B_s[tdd][ti * 4] =
        *(const float4*)&xdT[(12 + tdd) * RT + row0 + ti * 4];
    if (tid < 192)
        *(float4*)&dtr_s[tid >> 4][(tid & 15) * 4] =
            *(const float4*)&xdT[(tid >> 4) * RT + row0 + (tid & 15) * 4];
    float4 xv4 = *(const float4*)&xcT[(d0 + tdd) * RT + row0 + ti * 4];
    __syncthreads();
    float dtbv = dtb_s[tdd];
#pragma unroll
    for (int q = 0; q < 4; ++q) {
        int col = ti * 4 + q;
        float acc = dtbv;
#pragma unroll
        for (int rr = 0; rr < DT_RANK; ++rr)
            acc = fmaf(dtr_s[rr][col], dtw_s[tdd * DT_RANK + rr], acc);
        float dtv = fmaxf(acc, 0.f) + __logf(1.f + __expf(-fabsf(acc)));
        dt_s[tdd][col] = dtv;
        g_s[tdd][col]  = dtv * (&xv4.x)[q];
    }
    __syncthreads();
    float h = 0.f, Pacc = 1.f;
#pragma unroll
    for (int i = 0; i < SEGL; ++i) {
        float e = __expf(dt_s[dl][i] * a);
        Pacc *= e;
        h = fmaf(e, h, g_s[dl][i] * B_s[n][i]);
    }
    int idx = ((seg * BB + b) * DI + d0 + dl) * NS + n;
    P[idx] = Pacc;
    Hf[idx] = h;
}

// ---------------------------------------------------------------------------
// K4b: rescan each segment from folded h_init; 64 steps barrier-free with
// DPP rsum16 + rotating lane-capture epilogue; direct per-lane y writes.
__global__ __launch_bounds__(256) void scan_part2(const float* __restrict__ xdT,
                                                  const float* __restrict__ xcT,
                                                  const float* __restrict__ zsT,
                                                  const float* __restrict__ dtw,
                                                  const float* __restrict__ dtb,
                                                  const float* __restrict__ P,
                                                  const float* __restrict__ Hf,
                                                  const float* __restrict__ A_log,
                                                  const float* __restrict__ Dp,
                                                  float* __restrict__ yT) {
    __shared__ float dt_s[16][68], g_s[16][68], B_s[16][68], C_s[16][68],
                     xc_s[16][68];
    __shared__ float dtr_s[12][68];
    __shared__ float dtw_s[192];
    __shared__ float dtb_s[16];
    int seg = blockIdx.x, d0 = blockIdx.y * 16, b = blockIdx.z;
    int row0 = b * LL + seg * SEGL;
    int tid = threadIdx.x;
    int lane = tid & 63;
    int n = lane & 15;
    int dl = ((tid >> 6) << 2) | (lane >> 4);
    int d = d0 + dl;
    int tdd = tid >> 4, ti = tid & 15;
    if (tid < 192) dtw_s[tid] = dtw[d0 * DT_RANK + tid];
    if (tid < 16)  dtb_s[tid] = dtb[d0 + tid];
    float a = -__expf(A_log[d * NS + n]);
    float Dpv = Dp[d];
    *(float4*)&B_s[tdd][ti * 4] =
        *(const float4*)&xdT[(12 + tdd) * RT + row0 + ti * 4];
    *(float4*)&C_s[tdd][ti * 4] =
        *(const float4*)&xdT[(28 + tdd) * RT + row0 + ti * 4];
    if (tid < 192)
        *(float4*)&dtr_s[tid >> 4][(tid & 15) * 4] =
            *(const float4*)&xdT[(tid >> 4) * RT + row0 + (tid & 15) * 4];
    float4 xv4 = *(const float4*)&xcT[(d0 + tdd) * RT + row0 + ti * 4];
    float h = 0.f;
    for (int s = 0; s < seg; ++s) {
        int off = ((s * BB + b) * DI + d) * NS + n;
        h = fmaf(P[off], h, Hf[off]);
    }
    __syncthreads();
    float dtbv = dtb_s[tdd];
#pragma unroll
    for (int q = 0; q < 4; ++q) {
        int col = ti * 4 + q;
        float acc = dtbv;
#pragma unroll
        for (int rr = 0; rr < DT_RANK; ++rr)
            acc = fmaf(dtr_s[rr][col], dtw_s[tdd * DT_RANK + rr], acc);
        float dtv = fmaxf(acc, 0.f) + __logf(1.f + __expf(-fabsf(acc)));
        dt_s[tdd][col] = dtv;
        float xcv = (&xv4.x)[q];
        g_s[tdd][col]  = dtv * xcv;
        xc_s[tdd][col] = xcv;
    }
    __syncthreads();
#pragma unroll
    for (int w = 0; w < 4; ++w) {
        int i0 = w * 16;
        float scap = 0.f;
#pragma unroll
        for (int j = 0; j < 16; ++j) {
            int i = i0 + j;
            float e = __expf(dt_s[dl][i] * a);
            h = fmaf(e, h, g_s[dl][i] * B_s[n][i]);
            float s = rsum16(h * C_s[n][i]);
            scap = (n == j) ? s : scap;
        }
        float xcv = xc_s[dl][i0 + n];
        float zsv = zsT[(size_t)(d0 + dl) * RT + row0 + i0 + n];
        yT[(size_t)(d0 + dl) * RT + row0 + i0 + n] = fmaf(xcv, Dpv, scap) * zsv;
    }
}

// ---------------------------------------------------------------------------
// K5: out[b, c, l] = sum_d yT[d, row] * out_w[c, d]
// LDS-free, same pattern as K2: lane = row (yT coalesced, L2-resident),
// out_w wave-uniform -> SGPRs. Wave = 64 rows x 8 c. grid (128, 6), 256 thr.
__global__ __launch_bounds__(256) void gemm_out(const float* __restrict__ yT,
                                                const float* __restrict__ out_w,
                                                float* __restrict__ out) {
    int wv = __builtin_amdgcn_readfirstlane(threadIdx.x >> 6);
    int lane = threadIdx.x & 63;
    int r0 = blockIdx.x * 64;
    int b = r0 >> 10, l0 = r0 & 1023;
    int cw = blockIdx.y * 32 + wv * 8;   // this wave's 8-c strip
    const float* ybase = yT + r0 + lane;
    const float* wbase = out_w + (size_t)cw * DI;
    float acc[8] = {};
#pragma unroll 4
    for (int d = 0; d < DI; ++d) {
        float a = ybase[(size_t)d * RT];
#pragma unroll
        for (int ci = 0; ci < 8; ++ci)
            acc[ci] = fmaf(wbase[ci * DI + d], a, acc[ci]);   // s_load weight
    }
    float* ob = out + (size_t)b * CC * LL + l0 + lane;
#pragma unroll
    for (int ci = 0; ci < 8; ++ci)
        ob[(size_t)(cw + ci) * LL] = acc[ci];
}

// ---------------------------------------------------------------------------
extern "C" void kernel_launch(void* const* d_in, const int* in_sizes, int n_in,
                              void* d_out, int out_size, void* d_ws, size_t ws_size,
                              hipStream_t stream) {
    const float* x         = (const float*)d_in[0];
    const float* proj_w    = (const float*)d_in[1];
    const float* proj_b    = (const float*)d_in[2];
    const float* in_proj_w = (const float*)d_in[3];
    const float* conv_w    = (const float*)d_in[4];
    const float* conv_b    = (const float*)d_in[5];
    const float* xproj_w   = (const float*)d_in[6];
    const float* dtproj_w  = (const float*)d_in[7];
    const float* dtproj_b  = (const float*)d_in[8];
    const float* A_log     = (const float*)d_in[9];
    const float* Dp        = (const float*)d_in[10];
    const float* out_w     = (const float*)d_in[11];
    float* out = (float*)d_out;

    float* ws    = (float*)d_ws;
    float* W2    = ws;                    // 147456
    float* bias2 = W2 + 147456;           // 768
    float* xzT   = bias2 + 768;           // 768*8192 = 6291456 (x raw, z silu'd)
    float* xcT   = xzT + 6291456;         // 3145728
    float* yT    = xcT + 3145728;         // 3145728
    float* xdT   = yT + 3145728;          // 44*8192 = 360448 (0-11 dtr, 12-27 B, 28-43 C)
    float* P     = xdT + 360448;          // 786432
    float* Hf    = P + 786432;            // 786432
    float* zsT   = xzT + DI * RT;         // z half, silu applied by gemm_xz epilogue

    fuse_w_kernel<<<768, 192, 0, stream>>>(in_proj_w, proj_w, proj_b, W2, bias2);
    gemm_xz<<<dim3(64, 12), 256, 0, stream>>>(x, W2, bias2, xzT);
    xproj_conv_gemm<<<dim3(128, 2), 512, 0, stream>>>(xzT, conv_w, conv_b,
                                                      xproj_w, xcT, xdT);
    scan_part1<<<dim3(16, 24, 8), 256, 0, stream>>>(xdT, xcT, dtproj_w, dtproj_b,
                                                    A_log, P, Hf);
    scan_part2<<<dim3(16, 24, 8), 256, 0, stream>>>(xdT, xcT, zsT, dtproj_w, dtproj_b,
                                                    P, Hf, A_log, Dp, yT);
    gemm_out<<<dim3(128, 6), 256, 0, stream>>>(yT, out_w, out);
}